// Round 8
// baseline (377.135 us; speedup 1.0000x reference)
//
#include <hip/hip_runtime.h>
#include <type_traits>
#include <utility>

typedef unsigned short u16;
typedef unsigned int u32;
typedef __attribute__((ext_vector_type(8))) short short8;
typedef __attribute__((ext_vector_type(8))) __bf16 bhalf8;
typedef __attribute__((ext_vector_type(4))) short short4v;
typedef __attribute__((ext_vector_type(4))) __bf16 bhalf4;
typedef __attribute__((ext_vector_type(4))) float f32x4;
typedef __attribute__((ext_vector_type(4))) unsigned short us4;

#define S_LEN 2048
#define NHEAD 32
#define HD 80
#define HDP 96
#define HID 2560
#define N3 7680
#define QK_SCALE 0.11180339887498949f  // 80^-0.5
#define LOG2E 1.4426950408889634f

// ---------- MFMA K=32 wrapper (hedge: builtin may take __bf16x8 or shortx8) ----------
template <typename T, typename = void> struct MfmaTakes : std::false_type {};
template <typename T>
struct MfmaTakes<T, std::void_t<decltype(__builtin_amdgcn_mfma_f32_16x16x32_bf16(
                       std::declval<T>(), std::declval<T>(), std::declval<f32x4>(), 0, 0, 0))>>
    : std::true_type {};

template <typename AB>
__device__ inline f32x4 mfma_raw(AB a, AB b, f32x4 c) {
  return __builtin_amdgcn_mfma_f32_16x16x32_bf16(a, b, c, 0, 0, 0);
}
using mfma_ab_t = std::conditional_t<MfmaTakes<bhalf8>::value, bhalf8, short8>;
__device__ inline f32x4 MFMA(short8 a, short8 b, f32x4 c) {
  return mfma_raw<mfma_ab_t>(__builtin_bit_cast(mfma_ab_t, a),
                             __builtin_bit_cast(mfma_ab_t, b), c);
}

// ---------- MFMA K=16 wrapper (16x16x16 bf16), with emulation fallback ----------
#if defined(__has_builtin)
#if __has_builtin(__builtin_amdgcn_mfma_f32_16x16x16bf16_1k)
#define MFMA16_RAW(a, b, c) __builtin_amdgcn_mfma_f32_16x16x16bf16_1k(a, b, c, 0, 0, 0)
#define HAVE_MFMA16 1
#elif __has_builtin(__builtin_amdgcn_mfma_f32_16x16x16_bf16)
#define MFMA16_RAW(a, b, c) __builtin_amdgcn_mfma_f32_16x16x16_bf16(a, b, c, 0, 0, 0)
#define HAVE_MFMA16 1
#endif
#endif

#ifdef HAVE_MFMA16
template <typename T, typename = void> struct M16Takes : std::false_type {};
template <typename T>
struct M16Takes<T, std::void_t<decltype(MFMA16_RAW(std::declval<T>(), std::declval<T>(),
                                                   std::declval<f32x4>()))>> : std::true_type {};
using m16_t = std::conditional_t<M16Takes<bhalf4>::value, bhalf4, short4v>;
__device__ inline f32x4 MFMA16(short4v a, short4v b, f32x4 c) {
  return MFMA16_RAW(__builtin_bit_cast(m16_t, a), __builtin_bit_cast(m16_t, b), c);
}
#else
// Emulate K=16 via K=32 MFMA with zero upper k-half in BOTH operands.
__device__ inline f32x4 MFMA16(short4v a, short4v b, f32x4 c) {
  short8 a8 = {a[0], a[1], a[2], a[3], 0, 0, 0, 0};
  short8 b8 = {b[0], b[1], b[2], b[3], 0, 0, 0, 0};
  return MFMA(a8, b8, c);
}
#endif

__device__ inline float bf2f(u16 b) { return __uint_as_float(((u32)b) << 16); }
__device__ inline u16 f2bf(float f) {
  u32 u = __float_as_uint(f);
  u += 0x7fffu + ((u >> 16) & 1u);  // round-to-nearest-even
  return (u16)(u >> 16);
}

typedef __attribute__((address_space(1))) void as1_void;
typedef __attribute__((address_space(3))) void as3_void;

#if defined(__has_builtin)
#if __has_builtin(__builtin_amdgcn_global_load_lds)
#define HAVE_GLL 1
#endif
#endif

// Stage 16B/lane: global (per-lane addr) -> LDS (wave-uniform base + lane*16).
__device__ inline void stage16(const u16* g, u16* lds_base, int lane) {
#ifdef HAVE_GLL
  (void)lane;
  __builtin_amdgcn_global_load_lds((as1_void*)g, (as3_void*)lds_base, 16, 0, 0);
#else
  *(short8*)(lds_base + lane * 8) = *(const short8*)g;
#endif
}

__device__ inline void sched_barrier0() {
#if defined(__has_builtin)
#if __has_builtin(__builtin_amdgcn_sched_barrier)
  __builtin_amdgcn_sched_barrier(0);
#endif
#endif
}

// ---------- dtype detection: are the float tensors f32 or bf16 on device? ----------
__global__ __launch_bounds__(256) void detect_dtype(const u32* __restrict__ words,
                                                    int* __restrict__ flag) {
  __shared__ int red[256];
  int junk = 0;
  for (int i = threadIdx.x; i < 2048; i += 256) {
    u16 lo = (u16)(words[i] & 0xffffu);
    u32 e = (lo >> 7) & 0xffu;  // bf16 exponent field
    junk += (e >= 137u);        // |x| >= 1024, or NaN/Inf
  }
  red[threadIdx.x] = junk;
  __syncthreads();
  for (int s = 128; s > 0; s >>= 1) {
    if (threadIdx.x < s) red[threadIdx.x] += red[threadIdx.x + s];
    __syncthreads();
  }
  if (threadIdx.x == 0) flag[0] = (red[0] > 64) ? 1 : 0;  // 1 = f32, 0 = bf16
}

// ---------- hidden_states -> bf16 (contiguous) ----------
__global__ __launch_bounds__(256) void convert_hidden(const void* __restrict__ in,
                                                      u16* __restrict__ out, int n4,
                                                      const int* __restrict__ flagp) {
  const int f = *flagp;
  int i = blockIdx.x * 256 + threadIdx.x;
  if (i >= n4) return;
  if (f) {
    const float* inf = (const float*)in;
    us4 o;
#pragma unroll
    for (int j = 0; j < 4; ++j) o[j] = f2bf(inf[(size_t)i * 4 + j]);
    *(us4*)&out[(size_t)i * 4] = o;
  } else {
    *(us4*)&out[(size_t)i * 4] = *(const us4*)&((const u16*)in)[(size_t)i * 4];
  }
}

// ---------- vectorized 64x64 transpose (+optional f32->bf16 convert) ----------
__global__ __launch_bounds__(256) void transpose64(const void* __restrict__ in,
                                                   u16* __restrict__ out,
                                                   int istride, int ioff, int ostride,
                                                   const int* __restrict__ flagp) {
  __shared__ u16 tile[64][66];
  const int f = flagp ? *flagp : 0;
  const int bx = blockIdx.x * 64, by = blockIdx.y * 64;
  const int tx4 = (threadIdx.x & 15) * 4, ty = threadIdx.x >> 4;  // ty 0..15
#pragma unroll
  for (int i = 0; i < 4; ++i) {
    const int row = ty + i * 16;
    const size_t idx = (size_t)(by + row) * istride + ioff + bx + tx4;
    us4 v;
    if (f) {
      const f32x4 x = *(const f32x4*)&((const float*)in)[idx];
#pragma unroll
      for (int j = 0; j < 4; ++j) v[j] = f2bf(x[j]);
    } else {
      v = *(const us4*)&((const u16*)in)[idx];
    }
    *(u32*)&tile[row][tx4] = (u32)v[0] | ((u32)v[1] << 16);
    *(u32*)&tile[row][tx4 + 2] = (u32)v[2] | ((u32)v[3] << 16);
  }
  __syncthreads();
#pragma unroll
  for (int i = 0; i < 4; ++i) {
    const int oc = ty + i * 16;
    us4 o;
#pragma unroll
    for (int j = 0; j < 4; ++j) o[j] = tile[tx4 + j][oc];
    *(us4*)&out[(size_t)(bx + oc) * ostride + by + tx4] = o;
  }
}

// ---------- fused weight transposes: w_qkv and w_out in ONE launch ----------
// Grid (N3/64 + HID/64, HID/64). bx < N3/64 -> w_qkv [HID][N3] -> WtQ [N3][HID];
// else w_out [HID][HID] -> WtO [HID][HID]. Both outputs have row stride HID.
__global__ __launch_bounds__(256) void transpose_w2(const void* __restrict__ wq,
                                                    u16* __restrict__ WtQ,
                                                    const void* __restrict__ wo,
                                                    u16* __restrict__ WtO,
                                                    const int* __restrict__ flagp) {
  __shared__ u16 tile[64][66];
  const int f = *flagp;
  const int bxr = blockIdx.x;
  const void* in;
  u16* out;
  int istride, bx;
  if (bxr < N3 / 64) {
    in = wq; out = WtQ; istride = N3; bx = bxr * 64;
  } else {
    in = wo; out = WtO; istride = HID; bx = (bxr - N3 / 64) * 64;
  }
  const int by = blockIdx.y * 64;
  const int tx4 = (threadIdx.x & 15) * 4, ty = threadIdx.x >> 4;
#pragma unroll
  for (int i = 0; i < 4; ++i) {
    const int row = ty + i * 16;
    const size_t idx = (size_t)(by + row) * istride + bx + tx4;
    us4 v;
    if (f) {
      const f32x4 x = *(const f32x4*)&((const float*)in)[idx];
#pragma unroll
      for (int j = 0; j < 4; ++j) v[j] = f2bf(x[j]);
    } else {
      v = *(const us4*)&((const u16*)in)[idx];
    }
    *(u32*)&tile[row][tx4] = (u32)v[0] | ((u32)v[1] << 16);
    *(u32*)&tile[row][tx4 + 2] = (u32)v[2] | ((u32)v[3] << 16);
  }
  __syncthreads();
#pragma unroll
  for (int i = 0; i < 4; ++i) {
    const int oc = ty + i * 16;
    us4 o;
#pragma unroll
    for (int j = 0; j < 4; ++j) o[j] = tile[tx4 + j][oc];
    *(us4*)&out[(size_t)(bx + oc) * HID + by + tx4] = o;
  }
}

// ---------- 128x128 counted-lgkm GEMM (output GEMM), 3-buffer B / 1 barrier ----------
__global__ __launch_bounds__(256, 2) void gemm128c(const u16* __restrict__ A,
                                                   const u16* __restrict__ Bt,
                                                   void* __restrict__ C,
                                                   int M, int N, int K,
                                                   const int* __restrict__ flagp) {
  __shared__ u16 As[2][128 * 64];  // 2 x 16 KiB
  __shared__ u16 Bs[3][128 * 64];  // 3 x 16 KiB
  const int tid = threadIdx.x;
  const int w = tid >> 6, l = tid & 63, la = l & 15, qd = l >> 4;
  const int wr = w >> 1, wc = w & 1;
  const int of32 = flagp ? *flagp : 0;

  const int nbx = gridDim.x;
  const int nwg = nbx * gridDim.y;
  int lin = blockIdx.y * nbx + blockIdx.x;
  if ((nwg & 7) == 0) lin = (lin & 7) * (nwg >> 3) + (lin >> 3);
  const int m0 = (lin / nbx) * 128, n0 = (lin % nbx) * 128;
  const int NT = K >> 6;

  const int sx0 = (qd ^ (la & 7)) * 8;        // swizzled 16B-slot, kk=0
  const int sx1 = ((4 + qd) ^ (la & 7)) * 8;  // kk=1
  const int gsw = ((tid & 7) ^ ((tid >> 3) & 7)) * 8;  // inverse swizzle, global side

  f32x4 acc[4][4] = {};

  auto issue = [&](int s) {
    if (s >= NT * 4) return;
    const int kt = s >> 2, part = s & 3;
    const int h = part & 1;
    const u16* G = (part >= 2) ? A : Bt;
    const int b0 = (part >= 2) ? m0 : n0;
    u16* L = ((part >= 2) ? &As[kt & 1][0] : &Bs[kt % 3][0]) + h * 4096;
    const int k0 = kt << 6;
#pragma unroll
    for (int q = 0; q < 2; ++q) {
      const int row = h * 64 + q * 32 + (tid >> 3);
      const u16* g = G + (size_t)(b0 + row) * K + k0 + gsw;
      stage16(g, L + (q * 256 + w * 64) * 8, l);
    }
  };

  auto readA = [&](int buf, int mh, short8(&af)[2][2]) {
    const u16* base = &As[buf][0];
#pragma unroll
    for (int i = 0; i < 2; ++i) {
      const int ro = (wr * 64 + mh * 32 + i * 16 + la) * 64;
      af[i][0] = *(const short8*)(base + ro + sx0);
      af[i][1] = *(const short8*)(base + ro + sx1);
    }
  };
  auto readB = [&](int buf, int nh, short8(&bf)[2][2]) {
    const u16* base = &Bs[buf][0];
#pragma unroll
    for (int j = 0; j < 2; ++j) {
      const int ro = (wc * 64 + nh * 32 + j * 16 + la) * 64;
      bf[j][0] = *(const short8*)(base + ro + sx0);
      bf[j][1] = *(const short8*)(base + ro + sx1);
    }
  };
  auto quad = [&](short8(&af)[2][2], short8(&bf)[2][2], int mh, int nh) {
#pragma unroll
    for (int kk = 0; kk < 2; ++kk)
#pragma unroll
      for (int i = 0; i < 2; ++i)
#pragma unroll
        for (int jj = 0; jj < 2; ++jj)
          acc[mh * 2 + i][nh * 2 + jj] =
              MFMA(af[i][kk], bf[jj][kk], acc[mh * 2 + i][nh * 2 + jj]);
  };

#pragma unroll
  for (int s = 0; s < 6; ++s) issue(s);
  asm volatile("s_waitcnt vmcnt(4)" ::: "memory");
  __builtin_amdgcn_s_barrier();

  for (int t = 0; t < NT; ++t) {
    const int ab = t & 1, bb = t % 3;
    short8 af[2][2], af2[2][2], bf0[2][2], bf1[2][2];
    readA(ab, 0, af);   // 4 ds_read_b128
    sched_barrier0();
    readB(bb, 0, bf0);  // 4
    sched_barrier0();
    readB(bb, 1, bf1);  // 4
    sched_barrier0();
    issue(4 * t + 6);
    issue(4 * t + 7);
    issue(4 * t + 8);
    issue(4 * t + 9);
    asm volatile("s_waitcnt lgkmcnt(4)" ::: "memory");
    sched_barrier0();
    readA(ab, 1, af2);
    sched_barrier0();
    __builtin_amdgcn_s_setprio(1);
    quad(af, bf0, 0, 0);
    __builtin_amdgcn_s_setprio(0);
    asm volatile("s_waitcnt lgkmcnt(4)" ::: "memory");
    sched_barrier0();
    __builtin_amdgcn_s_setprio(1);
    quad(af, bf1, 0, 1);
    __builtin_amdgcn_s_setprio(0);
    asm volatile("s_waitcnt lgkmcnt(0)" ::: "memory");
    sched_barrier0();
    __builtin_amdgcn_s_setprio(1);
    quad(af2, bf0, 1, 0);
    quad(af2, bf1, 1, 1);
    __builtin_amdgcn_s_setprio(0);
    asm volatile("s_waitcnt vmcnt(4)" ::: "memory");
    __builtin_amdgcn_s_barrier();
  }

#pragma unroll
  for (int i = 0; i < 4; ++i)
#pragma unroll
    for (int j = 0; j < 4; ++j) {
      const int r0 = m0 + wr * 64 + (i >> 1) * 32 + (i & 1) * 16 + qd * 4;
      const int c0 = n0 + wc * 64 + (j >> 1) * 32 + (j & 1) * 16 + la;
#pragma unroll
      for (int r = 0; r < 4; ++r) {
        if (of32)
          ((float*)C)[(size_t)(r0 + r) * N + c0] = acc[i][j][r];
        else
          ((u16*)C)[(size_t)(r0 + r) * N + c0] = f2bf(acc[i][j][r]);
      }
    }
}

// ---------- 256x256 counted-lgkm GEMM, 3-buffer B / 1 barrier per tile ----------
// R7-verified (90.2 us, 0 conflicts, MfmaUtil 38%). Untouched this round.
__global__ __launch_bounds__(512, 2) void gemm256(const u16* __restrict__ A,
                                                  const u16* __restrict__ Bt,
                                                  u16* __restrict__ C,
                                                  int M, int N, int K) {
  __shared__ u16 As[2][256 * 64];  // 64 KiB
  __shared__ u16 Bs[3][256 * 64];  // 96 KiB
  const int tid = threadIdx.x;
  const int w = tid >> 6, l = tid & 63, la = l & 15, qd = l >> 4;
  const int wr = w >> 2, wc = w & 3;

  const int nbx = gridDim.x;
  const int nwg = nbx * gridDim.y;
  int lin = blockIdx.y * nbx + blockIdx.x;
  if ((nwg & 7) == 0) lin = (lin & 7) * (nwg >> 3) + (lin >> 3);
  const int m0 = (lin / nbx) * 256, n0 = (lin % nbx) * 256;
  const int NT = K >> 6;

  const int sx0 = (qd ^ (la & 7)) * 8;
  const int sx1 = ((4 + qd) ^ (la & 7)) * 8;
  const int gsw = ((tid & 7) ^ ((tid >> 3) & 7)) * 8;

  f32x4 acc[8][4] = {};

  auto issue = [&](int s) {
    if (s >= NT * 4) return;
    const int kt = s >> 2, part = s & 3;
    const int h = part & 1;
    const u16* G = (part >= 2) ? A : Bt;
    const int b0 = (part >= 2) ? m0 : n0;
    u16* L = ((part >= 2) ? &As[kt & 1][0] : &Bs[kt % 3][0]) + h * 8192;
    const int k0 = kt << 6;
#pragma unroll
    for (int q = 0; q < 2; ++q) {
      const int row = h * 128 + q * 64 + (tid >> 3);
      const u16* g = G + (size_t)(b0 + row) * K + k0 + gsw;
      stage16(g, L + (q * 512 + w * 64) * 8, l);
    }
  };

  auto readA = [&](int buf, int mh, short8(&af)[4][2]) {
    const u16* base = &As[buf][0];
#pragma unroll
    for (int i = 0; i < 4; ++i) {
      const int ro = (wr * 128 + mh * 64 + i * 16 + la) * 64;
      af[i][0] = *(const short8*)(base + ro + sx0);
      af[i][1] = *(const short8*)(base + ro + sx1);
    }
  };
  auto readB = [&](int buf, int nh, short8(&bf)[2][2]) {
    const u16* base = &Bs[buf][0];
#pragma unroll
    for (int j = 0; j < 2; ++j) {
      const int ro = (wc * 64 + nh * 32 + j * 16 + la) * 64;
      bf[j][0] = *(const short8*)(base + ro + sx0);
      bf[j][1] = *(const short8*)(base + ro + sx1);
    }
  };
  auto quad = [&](short8(&af)[4][2], short8(&bf)[2][2], int mh, int nh) {
#pragma unroll
    for (int kk = 0; kk < 2; ++kk)
#pragma unroll
      for (int i = 0; i < 4; ++i)
#pragma unroll
        for (int jj = 0; jj < 2; ++jj)
          acc[mh * 4 + i][nh * 2 + jj] =
              MFMA(af[i][kk], bf[jj][kk], acc[mh * 4 + i][nh * 2 + jj]);
  };

#pragma unroll
  for (int s = 0; s < 6; ++s) issue(s);
  asm volatile("s_waitcnt vmcnt(4)" ::: "memory");
  __builtin_amdgcn_s_barrier();

  for (int t = 0; t < NT; ++t) {
    const int ab = t & 1, bb = t % 3;
    short8 af[4][2], af2[4][2], bf0[2][2], bf1[2][2];
    readA(ab, 0, af);
    sched_barrier0();
    readB(bb, 0, bf0);
    sched_barrier0();
    readB(bb, 1, bf1);
    sched_barrier0();
    issue(4 * t + 6);
    issue(4 * t + 7);
    issue(4 * t + 8);
    issue(4 * t + 9);
    asm volatile("s_waitcnt lgkmcnt(4)" ::: "memory");
    sched_barrier0();
    readA(ab, 1, af2);
    sched_barrier0();
    __builtin_amdgcn_s_setprio(1);
    quad(af, bf0, 0, 0);
    __builtin_amdgcn_s_setprio(0);
    asm volatile("s_waitcnt lgkmcnt(8)" ::: "memory");
    sched_barrier0();
    __builtin_amdgcn_s_setprio(1);
    quad(af, bf1, 0, 1);
    __builtin_amdgcn_s_setprio(0);
    asm volatile("s_waitcnt lgkmcnt(0)" ::: "memory");
    sched_barrier0();
    __builtin_amdgcn_s_setprio(1);
    quad(af2, bf0, 1, 0);
    quad(af2, bf1, 1, 1);
    __builtin_amdgcn_s_setprio(0);
    asm volatile("s_waitcnt vmcnt(4)" ::: "memory");
    __builtin_amdgcn_s_barrier();
  }

#pragma unroll
  for (int i = 0; i < 8; ++i)
#pragma unroll
    for (int j = 0; j < 4; ++j) {
      const int r0 = m0 + wr * 128 + i * 16 + qd * 4;
      const int c0 = n0 + wc * 64 + j * 16 + la;
#pragma unroll
      for (int r = 0; r < 4; ++r)
        C[(size_t)(r0 + r) * N + c0] = f2bf(acc[i][j][r]);
    }
}

// ---------- RoPE prep ----------
__global__ __launch_bounds__(256) void rope_prep(const u16* __restrict__ qkv,
                                                 const int* __restrict__ pos,
                                                 u16* __restrict__ Qh,
                                                 u16* __restrict__ Kt) {
  const int s = blockIdx.x;
  const int h = blockIdx.y * 4 + (threadIdx.x >> 6);
  const int t = threadIdx.x & 63;
  const size_t qin = (size_t)s * N3 + h * HD;
  const size_t kin = qin + HID;
  const size_t ob = ((size_t)h * S_LEN + s) * HDP;
  const size_t kb = ((size_t)(h * 32) + (s >> 6)) * 6144 + (size_t)(s & 63) * 8;
  if (t < 32) {
    const float p = (float)pos[s];
    const float inv = exp2f(-(float)t * (13.287712379549449f / 32.0f));
    const float ang = p * inv;
    const float cs = cosf(ang), sn = sinf(ang);
    float x1 = bf2f(qkv[qin + t]), x2 = bf2f(qkv[qin + t + 32]);
    Qh[ob + t] = f2bf(x1 * cs - x2 * sn);
    Qh[ob + t + 32] = f2bf(x2 * cs + x1 * sn);
    x1 = bf2f(qkv[kin + t]);
    x2 = bf2f(qkv[kin + t + 32]);
    Kt[kb + (size_t)(t >> 3) * 512 + (t & 7)] = f2bf(x1 * cs - x2 * sn);
    const int d2 = t + 32;
    Kt[kb + (size_t)(d2 >> 3) * 512 + (d2 & 7)] = f2bf(x2 * cs + x1 * sn);
  } else if (t < 48) {
    const int d = t + 32;  // 64..79 pass-through
    Qh[ob + d] = qkv[qin + d];
    Kt[kb + (size_t)(d >> 3) * 512 + (d & 7)] = qkv[kin + d];
  } else {
    const int d = t + 32;  // 80..95 zero pad
    Qh[ob + d] = 0;
    Kt[kb + (size_t)(d >> 3) * 512 + (d & 7)] = 0;
  }
}

// ---------- Fused causal+ALiBi flash attention, uniform sub-block pairs ----------
// Grid (16, 32) = 512 blocks of 256 threads (4 waves x 16 q-rows = 64 rows).
// Block x -> pair = x>>1, half = (x&1)^(h>=16); runs segment A = rows
// [ (15-pair)*128 + half*64 , +64 ) then segment B = [ pair*128 + half*64, +64).
// Per-block iterations = 32 + 2*half; CU c hosts (x,h) and (x,h+16) -> halves
// 0 and 1 -> 66 iters/CU uniform AND both blocks live the whole kernel, so the
// 2-block overlap covers every barrier (R6's one-tile blocks overlapped only
// while the short partner was alive). LDS 45 KiB, ~116 VGPR -> 2 blocks/CU.
__global__ __launch_bounds__(256) void attn_fused(const u16* __restrict__ Qh,
                                                  const u16* __restrict__ Kt,
                                                  const u16* __restrict__ Vt,
                                                  u16* __restrict__ AO) {
  __shared__ u16 Ks[2][768 * 8];  // 2 x 12288 B (12 slots x 64 rows x 16 B)
  __shared__ u16 Vs[2][640 * 8];  // 2 x 10240 B (swizzled columns)
  const int tid = threadIdx.x, w = tid >> 6, l = tid & 63;
  const int la = l & 15, qd = l >> 4;
  const int h = blockIdx.y;
  const int x = blockIdx.x;  // 0..15
  const int pair = x >> 1;
  const int half = (x & 1) ^ (h >> 4);
  const int q0A = (15 - pair) * 128 + half * 64;  // long segment first
  const int q0B = pair * 128 + half * 64;
  const int nItA = (q0A >> 6) + 1;
  const int nItB = (q0B >> 6) + 1;
  const size_t hS = (size_t)h * S_LEN;

  short8 qfA[3], qfB[3];
#pragma unroll
  for (int c = 0; c < 3; ++c) {
    qfA[c] = *(const short8*)&Qh[(hS + q0A + w * 16 + la) * HDP + c * 32 + qd * 8];
    qfB[c] = *(const short8*)&Qh[(hS + q0B + w * 16 + la) * HDP + c * 32 + qd * 8];
  }

  const float slope2 = exp2f(-0.25f * (float)(h + 1)) * LOG2E;
  const float scl2 = QK_SCALE * LOG2E;
  float m_i = -1e30f, l_i = 0.f;
  f32x4 acc[5] = {};

  const u16* gK = Kt + (size_t)h * 32 * 6144;
  const u16* gV = Vt + (size_t)h * HD * S_LEN;

  // 256-thread staging: K = 768 chunks (3 rounds), V = 640 chunks (2.5 rounds,
  // wave-uniform guard). K linear; V gathered with inverse column swizzle.
  auto stage = [&](int kt_g, int buf) {
    const u16* gkt = gK + (size_t)kt_g * 6144;
#pragma unroll
    for (int j = 0; j < 3; ++j)
      stage16(gkt + (size_t)(j * 256 + tid) * 8, &Ks[buf][(j * 256 + w * 64) * 8], l);
    const u16* gv = gV + (kt_g << 6);
#pragma unroll
    for (int j = 0; j < 3; ++j) {
      const int c0 = j * 256 + w * 64;
      if (c0 < 640) {  // wave-uniform guard
        const int c = c0 + l;
        const int row = c >> 3, seg = c & 7;
        const int gcol = ((seg - (row & 7)) & 7) * 8;
        stage16(gv + (size_t)row * S_LEN + gcol, &Vs[buf][c0 * 8], l);
      }
    }
  };

  int g = 0;  // global iteration counter (buffer parity across segments)
  stage(0, 0);

  auto run_seg = [&](const short8(&qf)[3], int q0, int nIt, bool more) {
    const int qb = q0 + w * 16;
    const int q = qb + la;
    for (int it = 0; it < nIt; ++it, ++g) {
      const int buf = g & 1;
      __syncthreads();  // stage(g) complete; all waves done with buf^1
      if (it + 1 < nIt) stage(it + 1, buf ^ 1);
      else if (more) stage(0, buf ^ 1);  // restart key stream for next segment
      const int k0 = it << 6;
      if (k0 >= qb + 16) continue;  // wave-uniform skip of fully-masked tiles

      // --- S^T tiles from LDS (lane-contiguous reads of the tiled K) ---
      f32x4 st[4];
#pragma unroll
      for (int kt = 0; kt < 4; ++kt) {
        short8 kf[3];
#pragma unroll
        for (int c = 0; c < 3; ++c)
          kf[c] = *(const short8*)&Ks[buf][((c * 4 + qd) * 64 + kt * 16 + la) * 8];
        f32x4 z = {};
#pragma unroll
        for (int c = 0; c < 3; ++c) z = MFMA(kf[c], qf[c], z);
        st[kt] = z;
      }

      // --- mask + scale (log2 domain) ---
      const float base = (float)(k0 + qd * 4 - q);  // rel = base + (kt*16 + r)
      float mloc = -1e30f;
      if (k0 + 64 <= qb + 1) {  // tile fully unmasked for every lane of wave
#pragma unroll
        for (int kt = 0; kt < 4; ++kt)
#pragma unroll
          for (int r = 0; r < 4; ++r) {
            const float rel = base + (float)(kt * 16 + r);
            const float v = st[kt][r] * scl2 + slope2 * rel;
            st[kt][r] = v;
            mloc = fmaxf(mloc, v);
          }
      } else {
#pragma unroll
        for (int kt = 0; kt < 4; ++kt)
#pragma unroll
          for (int r = 0; r < 4; ++r) {
            const float rel = base + (float)(kt * 16 + r);
            const float v = (rel <= 0.f) ? st[kt][r] * scl2 + slope2 * rel : -1e30f;
            st[kt][r] = v;
            mloc = fmaxf(mloc, v);
          }
      }
      mloc = fmaxf(mloc, __shfl_xor(mloc, 16));
      mloc = fmaxf(mloc, __shfl_xor(mloc, 32));

      // --- defer-max (T13): rescale only when the max actually grew ---
      if (!__all(mloc - m_i <= 8.0f)) {
        const float nm = fmaxf(m_i, mloc);
        const float al = exp2f(m_i - nm);
        m_i = nm;
        l_i *= al;
#pragma unroll
        for (int dt = 0; dt < 5; ++dt) acc[dt] *= al;
      }

      float ps = 0.f;
      short4v pf[4];
#pragma unroll
      for (int kt = 0; kt < 4; ++kt) {
        short4v pk;
#pragma unroll
        for (int r = 0; r < 4; ++r) {
          const float pv = exp2f(st[kt][r] - m_i);
          ps += pv;
          pk[r] = (short)f2bf(pv);
        }
        pf[kt] = pk;
      }
      ps += __shfl_xor(ps, 16);
      ps += __shfl_xor(ps, 32);
      l_i += ps;

      // --- PV from LDS (swizzled, conflict-free b64): O^T += V^T * P^T ---
      const int cb = qd * 4 + ((la & 7) << 3);
#pragma unroll
      for (int dt = 0; dt < 5; ++dt) {
        const int vrow = (dt * 16 + la) * 64;
#pragma unroll
        for (int kt = 0; kt < 4; ++kt) {
          const short4v vf = *(const short4v*)&Vs[buf][vrow + ((kt * 16 + cb) & 63)];
          acc[dt] = MFMA16(vf, pf[kt], acc[dt]);
        }
      }
    }
    // --- epilogue for this segment: lane holds O^T[d=dt*16+qd*4+r][q] ---
    const float inv = 1.0f / l_i;
    const size_t row = (size_t)q;
#pragma unroll
    for (int dt = 0; dt < 5; ++dt) {
      us4 o;
#pragma unroll
      for (int r = 0; r < 4; ++r) o[r] = f2bf(acc[dt][r] * inv);
      *(us4*)&AO[row * HID + h * HD + dt * 16 + qd * 4] = o;
    }
    m_i = -1e30f;
    l_i = 0.f;
#pragma unroll
    for (int dt = 0; dt < 5; ++dt) acc[dt] = f32x4{};
  };

  run_seg(qfA, q0A, nItA, true);
  run_seg(qfB, q0B, nItB, false);
}

extern "C" void kernel_launch(void* const* d_in, const int* in_sizes, int n_in,
                              void* d_out, int out_size, void* d_ws, size_t ws_size,
                              hipStream_t stream) {
  const int* pos = (const int*)d_in[0];
  const void* hidden = d_in[1];
  const void* w_qkv = d_in[2];
  const void* w_out = d_in[3];
  u16* ws = (u16*)d_ws;

  // ws layout (u16 elements). Hb dead after GEMM1 -> Vt aliases it (same size).
  // WtQ dead after GEMM1 -> Qh/Kh/AO alias into it (17.8M <= 19.66M).
  u16* Hb = ws;                                  //  5,242,880
  u16* WtQ = Hb + (size_t)S_LEN * HID;           // 19,660,800
  u16* WtO = WtQ + (size_t)N3 * HID;             //  6,553,600
  u16* qkv = WtO + (size_t)HID * HID;            // 15,728,640
  int* flag = (int*)(qkv + (size_t)S_LEN * N3);  // 1 int
  u16* Vt = Hb;                                  //  5,242,880 (alias)
  u16* Qh = WtQ;                                 //  6,291,456 (alias)
  u16* Kh = Qh + (size_t)NHEAD * S_LEN * HDP;    //  6,291,456 (alias, tiled layout)
  u16* AO = Kh + (size_t)NHEAD * S_LEN * HDP;    //  5,242,880 (alias)

  detect_dtype<<<1, 256, 0, stream>>>((const u32*)hidden, flag);
  convert_hidden<<<(S_LEN * HID / 4 + 255) / 256, 256, 0, stream>>>(hidden, Hb,
                                                                    S_LEN * HID / 4, flag);
  // fused: w_qkv [HID][N3] -> WtQ and w_out [HID][HID] -> WtO
  transpose_w2<<<dim3(N3 / 64 + HID / 64, HID / 64), 256, 0, stream>>>(w_qkv, WtQ, w_out,
                                                                       WtO, flag);
  gemm256<<<dim3(N3 / 256, S_LEN / 256), 512, 0, stream>>>(Hb, WtQ, qkv, S_LEN, N3, HID);
  // qkv[s][2*HID + c] -> Vt[c][s]
  transpose64<<<dim3(HID / 64, S_LEN / 64), 256, 0, stream>>>(qkv, Vt, N3, 2 * HID, S_LEN,
                                                              nullptr);
  rope_prep<<<dim3(S_LEN, NHEAD / 4), 256, 0, stream>>>(qkv, pos, Qh, Kh);
  attn_fused<<<dim3(16, NHEAD), 256, 0, stream>>>(Qh, Kh, Vt, AO);
  gemm128c<<<dim3(HID / 128, S_LEN / 128), 256, 0, stream>>>(AO, WtO, d_out, S_LEN, HID,
                                                             HID, flag);
}

// Round 9
// 374.749 us; speedup vs baseline: 1.0064x; 1.0064x over previous
//
#include <hip/hip_runtime.h>
#include <type_traits>
#include <utility>

typedef unsigned short u16;
typedef unsigned int u32;
typedef __attribute__((ext_vector_type(8))) short short8;
typedef __attribute__((ext_vector_type(8))) __bf16 bhalf8;
typedef __attribute__((ext_vector_type(4))) short short4v;
typedef __attribute__((ext_vector_type(4))) __bf16 bhalf4;
typedef __attribute__((ext_vector_type(4))) float f32x4;
typedef __attribute__((ext_vector_type(4))) unsigned short us4;

#define S_LEN 2048
#define NHEAD 32
#define HD 80
#define HDP 96
#define HID 2560
#define N3 7680
#define QK_SCALE 0.11180339887498949f  // 80^-0.5
#define LOG2E 1.4426950408889634f

// ---------- MFMA K=32 wrapper (hedge: builtin may take __bf16x8 or shortx8) ----------
template <typename T, typename = void> struct MfmaTakes : std::false_type {};
template <typename T>
struct MfmaTakes<T, std::void_t<decltype(__builtin_amdgcn_mfma_f32_16x16x32_bf16(
                       std::declval<T>(), std::declval<T>(), std::declval<f32x4>(), 0, 0, 0))>>
    : std::true_type {};

template <typename AB>
__device__ inline f32x4 mfma_raw(AB a, AB b, f32x4 c) {
  return __builtin_amdgcn_mfma_f32_16x16x32_bf16(a, b, c, 0, 0, 0);
}
using mfma_ab_t = std::conditional_t<MfmaTakes<bhalf8>::value, bhalf8, short8>;
__device__ inline f32x4 MFMA(short8 a, short8 b, f32x4 c) {
  return mfma_raw<mfma_ab_t>(__builtin_bit_cast(mfma_ab_t, a),
                             __builtin_bit_cast(mfma_ab_t, b), c);
}

// ---------- MFMA K=16 wrapper (16x16x16 bf16), with emulation fallback ----------
#if defined(__has_builtin)
#if __has_builtin(__builtin_amdgcn_mfma_f32_16x16x16bf16_1k)
#define MFMA16_RAW(a, b, c) __builtin_amdgcn_mfma_f32_16x16x16bf16_1k(a, b, c, 0, 0, 0)
#define HAVE_MFMA16 1
#elif __has_builtin(__builtin_amdgcn_mfma_f32_16x16x16_bf16)
#define MFMA16_RAW(a, b, c) __builtin_amdgcn_mfma_f32_16x16x16_bf16(a, b, c, 0, 0, 0)
#define HAVE_MFMA16 1
#endif
#endif

#ifdef HAVE_MFMA16
template <typename T, typename = void> struct M16Takes : std::false_type {};
template <typename T>
struct M16Takes<T, std::void_t<decltype(MFMA16_RAW(std::declval<T>(), std::declval<T>(),
                                                   std::declval<f32x4>()))>> : std::true_type {};
using m16_t = std::conditional_t<M16Takes<bhalf4>::value, bhalf4, short4v>;
__device__ inline f32x4 MFMA16(short4v a, short4v b, f32x4 c) {
  return MFMA16_RAW(__builtin_bit_cast(m16_t, a), __builtin_bit_cast(m16_t, b), c);
}
#else
// Emulate K=16 via K=32 MFMA with zero upper k-half in BOTH operands.
__device__ inline f32x4 MFMA16(short4v a, short4v b, f32x4 c) {
  short8 a8 = {a[0], a[1], a[2], a[3], 0, 0, 0, 0};
  short8 b8 = {b[0], b[1], b[2], b[3], 0, 0, 0, 0};
  return MFMA(a8, b8, c);
}
#endif

__device__ inline float bf2f(u16 b) { return __uint_as_float(((u32)b) << 16); }
__device__ inline u16 f2bf(float f) {
  u32 u = __float_as_uint(f);
  u += 0x7fffu + ((u >> 16) & 1u);  // round-to-nearest-even
  return (u16)(u >> 16);
}

typedef __attribute__((address_space(1))) void as1_void;
typedef __attribute__((address_space(3))) void as3_void;

#if defined(__has_builtin)
#if __has_builtin(__builtin_amdgcn_global_load_lds)
#define HAVE_GLL 1
#endif
#endif

// Stage 16B/lane: global (per-lane addr) -> LDS (wave-uniform base + lane*16).
__device__ inline void stage16(const u16* g, u16* lds_base, int lane) {
#ifdef HAVE_GLL
  (void)lane;
  __builtin_amdgcn_global_load_lds((as1_void*)g, (as3_void*)lds_base, 16, 0, 0);
#else
  *(short8*)(lds_base + lane * 8) = *(const short8*)g;
#endif
}

__device__ inline void sched_barrier0() {
#if defined(__has_builtin)
#if __has_builtin(__builtin_amdgcn_sched_barrier)
  __builtin_amdgcn_sched_barrier(0);
#endif
#endif
}

// ---------- dtype detection: are the float tensors f32 or bf16 on device? ----------
__global__ __launch_bounds__(256) void detect_dtype(const u32* __restrict__ words,
                                                    int* __restrict__ flag) {
  __shared__ int red[256];
  int junk = 0;
  for (int i = threadIdx.x; i < 2048; i += 256) {
    u16 lo = (u16)(words[i] & 0xffffu);
    u32 e = (lo >> 7) & 0xffu;  // bf16 exponent field
    junk += (e >= 137u);        // |x| >= 1024, or NaN/Inf
  }
  red[threadIdx.x] = junk;
  __syncthreads();
  for (int s = 128; s > 0; s >>= 1) {
    if (threadIdx.x < s) red[threadIdx.x] += red[threadIdx.x + s];
    __syncthreads();
  }
  if (threadIdx.x == 0) flag[0] = (red[0] > 64) ? 1 : 0;  // 1 = f32, 0 = bf16
}

// ---------- hidden_states -> bf16 (contiguous) ----------
__global__ __launch_bounds__(256) void convert_hidden(const void* __restrict__ in,
                                                      u16* __restrict__ out, int n4,
                                                      const int* __restrict__ flagp) {
  const int f = *flagp;
  int i = blockIdx.x * 256 + threadIdx.x;
  if (i >= n4) return;
  if (f) {
    const float* inf = (const float*)in;
    us4 o;
#pragma unroll
    for (int j = 0; j < 4; ++j) o[j] = f2bf(inf[(size_t)i * 4 + j]);
    *(us4*)&out[(size_t)i * 4] = o;
  } else {
    *(us4*)&out[(size_t)i * 4] = *(const us4*)&((const u16*)in)[(size_t)i * 4];
  }
}

// ---------- vectorized 64x64 transpose (+optional f32->bf16 convert) ----------
__global__ __launch_bounds__(256) void transpose64(const void* __restrict__ in,
                                                   u16* __restrict__ out,
                                                   int istride, int ioff, int ostride,
                                                   const int* __restrict__ flagp) {
  __shared__ u16 tile[64][66];
  const int f = flagp ? *flagp : 0;
  const int bx = blockIdx.x * 64, by = blockIdx.y * 64;
  const int tx4 = (threadIdx.x & 15) * 4, ty = threadIdx.x >> 4;  // ty 0..15
#pragma unroll
  for (int i = 0; i < 4; ++i) {
    const int row = ty + i * 16;
    const size_t idx = (size_t)(by + row) * istride + ioff + bx + tx4;
    us4 v;
    if (f) {
      const f32x4 x = *(const f32x4*)&((const float*)in)[idx];
#pragma unroll
      for (int j = 0; j < 4; ++j) v[j] = f2bf(x[j]);
    } else {
      v = *(const us4*)&((const u16*)in)[idx];
    }
    *(u32*)&tile[row][tx4] = (u32)v[0] | ((u32)v[1] << 16);
    *(u32*)&tile[row][tx4 + 2] = (u32)v[2] | ((u32)v[3] << 16);
  }
  __syncthreads();
#pragma unroll
  for (int i = 0; i < 4; ++i) {
    const int oc = ty + i * 16;
    us4 o;
#pragma unroll
    for (int j = 0; j < 4; ++j) o[j] = tile[tx4 + j][oc];
    *(us4*)&out[(size_t)(bx + oc) * ostride + by + tx4] = o;
  }
}

// ---------- fused weight transposes: w_qkv and w_out in ONE launch ----------
__global__ __launch_bounds__(256) void transpose_w2(const void* __restrict__ wq,
                                                    u16* __restrict__ WtQ,
                                                    const void* __restrict__ wo,
                                                    u16* __restrict__ WtO,
                                                    const int* __restrict__ flagp) {
  __shared__ u16 tile[64][66];
  const int f = *flagp;
  const int bxr = blockIdx.x;
  const void* in;
  u16* out;
  int istride, bx;
  if (bxr < N3 / 64) {
    in = wq; out = WtQ; istride = N3; bx = bxr * 64;
  } else {
    in = wo; out = WtO; istride = HID; bx = (bxr - N3 / 64) * 64;
  }
  const int by = blockIdx.y * 64;
  const int tx4 = (threadIdx.x & 15) * 4, ty = threadIdx.x >> 4;
#pragma unroll
  for (int i = 0; i < 4; ++i) {
    const int row = ty + i * 16;
    const size_t idx = (size_t)(by + row) * istride + bx + tx4;
    us4 v;
    if (f) {
      const f32x4 x = *(const f32x4*)&((const float*)in)[idx];
#pragma unroll
      for (int j = 0; j < 4; ++j) v[j] = f2bf(x[j]);
    } else {
      v = *(const us4*)&((const u16*)in)[idx];
    }
    *(u32*)&tile[row][tx4] = (u32)v[0] | ((u32)v[1] << 16);
    *(u32*)&tile[row][tx4 + 2] = (u32)v[2] | ((u32)v[3] << 16);
  }
  __syncthreads();
#pragma unroll
  for (int i = 0; i < 4; ++i) {
    const int oc = ty + i * 16;
    us4 o;
#pragma unroll
    for (int j = 0; j < 4; ++j) o[j] = tile[tx4 + j][oc];
    *(us4*)&out[(size_t)(bx + oc) * HID + by + tx4] = o;
  }
}

// ---------- 128x128 counted-lgkm GEMM (output GEMM), 3-buffer B / 1 barrier ----------
__global__ __launch_bounds__(256, 2) void gemm128c(const u16* __restrict__ A,
                                                   const u16* __restrict__ Bt,
                                                   void* __restrict__ C,
                                                   int M, int N, int K,
                                                   const int* __restrict__ flagp) {
  __shared__ u16 As[2][128 * 64];  // 2 x 16 KiB
  __shared__ u16 Bs[3][128 * 64];  // 3 x 16 KiB
  const int tid = threadIdx.x;
  const int w = tid >> 6, l = tid & 63, la = l & 15, qd = l >> 4;
  const int wr = w >> 1, wc = w & 1;
  const int of32 = flagp ? *flagp : 0;

  const int nbx = gridDim.x;
  const int nwg = nbx * gridDim.y;
  int lin = blockIdx.y * nbx + blockIdx.x;
  if ((nwg & 7) == 0) lin = (lin & 7) * (nwg >> 3) + (lin >> 3);
  const int m0 = (lin / nbx) * 128, n0 = (lin % nbx) * 128;
  const int NT = K >> 6;

  const int sx0 = (qd ^ (la & 7)) * 8;        // swizzled 16B-slot, kk=0
  const int sx1 = ((4 + qd) ^ (la & 7)) * 8;  // kk=1
  const int gsw = ((tid & 7) ^ ((tid >> 3) & 7)) * 8;  // inverse swizzle, global side

  f32x4 acc[4][4] = {};

  auto issue = [&](int s) {
    if (s >= NT * 4) return;
    const int kt = s >> 2, part = s & 3;
    const int h = part & 1;
    const u16* G = (part >= 2) ? A : Bt;
    const int b0 = (part >= 2) ? m0 : n0;
    u16* L = ((part >= 2) ? &As[kt & 1][0] : &Bs[kt % 3][0]) + h * 4096;
    const int k0 = kt << 6;
#pragma unroll
    for (int q = 0; q < 2; ++q) {
      const int row = h * 64 + q * 32 + (tid >> 3);
      const u16* g = G + (size_t)(b0 + row) * K + k0 + gsw;
      stage16(g, L + (q * 256 + w * 64) * 8, l);
    }
  };

  auto readA = [&](int buf, int mh, short8(&af)[2][2]) {
    const u16* base = &As[buf][0];
#pragma unroll
    for (int i = 0; i < 2; ++i) {
      const int ro = (wr * 64 + mh * 32 + i * 16 + la) * 64;
      af[i][0] = *(const short8*)(base + ro + sx0);
      af[i][1] = *(const short8*)(base + ro + sx1);
    }
  };
  auto readB = [&](int buf, int nh, short8(&bf)[2][2]) {
    const u16* base = &Bs[buf][0];
#pragma unroll
    for (int j = 0; j < 2; ++j) {
      const int ro = (wc * 64 + nh * 32 + j * 16 + la) * 64;
      bf[j][0] = *(const short8*)(base + ro + sx0);
      bf[j][1] = *(const short8*)(base + ro + sx1);
    }
  };
  auto quad = [&](short8(&af)[2][2], short8(&bf)[2][2], int mh, int nh) {
#pragma unroll
    for (int kk = 0; kk < 2; ++kk)
#pragma unroll
      for (int i = 0; i < 2; ++i)
#pragma unroll
        for (int jj = 0; jj < 2; ++jj)
          acc[mh * 2 + i][nh * 2 + jj] =
              MFMA(af[i][kk], bf[jj][kk], acc[mh * 2 + i][nh * 2 + jj]);
  };

#pragma unroll
  for (int s = 0; s < 6; ++s) issue(s);
  asm volatile("s_waitcnt vmcnt(4)" ::: "memory");
  __builtin_amdgcn_s_barrier();

  for (int t = 0; t < NT; ++t) {
    const int ab = t & 1, bb = t % 3;
    short8 af[2][2], af2[2][2], bf0[2][2], bf1[2][2];
    readA(ab, 0, af);   // 4 ds_read_b128
    sched_barrier0();
    readB(bb, 0, bf0);  // 4
    sched_barrier0();
    readB(bb, 1, bf1);  // 4
    sched_barrier0();
    issue(4 * t + 6);
    issue(4 * t + 7);
    issue(4 * t + 8);
    issue(4 * t + 9);
    asm volatile("s_waitcnt lgkmcnt(4)" ::: "memory");
    sched_barrier0();
    readA(ab, 1, af2);
    sched_barrier0();
    __builtin_amdgcn_s_setprio(1);
    quad(af, bf0, 0, 0);
    __builtin_amdgcn_s_setprio(0);
    asm volatile("s_waitcnt lgkmcnt(4)" ::: "memory");
    sched_barrier0();
    __builtin_amdgcn_s_setprio(1);
    quad(af, bf1, 0, 1);
    __builtin_amdgcn_s_setprio(0);
    asm volatile("s_waitcnt lgkmcnt(0)" ::: "memory");
    sched_barrier0();
    __builtin_amdgcn_s_setprio(1);
    quad(af2, bf0, 1, 0);
    quad(af2, bf1, 1, 1);
    __builtin_amdgcn_s_setprio(0);
    asm volatile("s_waitcnt vmcnt(4)" ::: "memory");
    __builtin_amdgcn_s_barrier();
  }

#pragma unroll
  for (int i = 0; i < 4; ++i)
#pragma unroll
    for (int j = 0; j < 4; ++j) {
      const int r0 = m0 + wr * 64 + (i >> 1) * 32 + (i & 1) * 16 + qd * 4;
      const int c0 = n0 + wc * 64 + (j >> 1) * 32 + (j & 1) * 16 + la;
#pragma unroll
      for (int r = 0; r < 4; ++r) {
        if (of32)
          ((float*)C)[(size_t)(r0 + r) * N + c0] = acc[i][j][r];
        else
          ((u16*)C)[(size_t)(r0 + r) * N + c0] = f2bf(acc[i][j][r]);
      }
    }
}

// ---------- 256x256 counted-lgkm GEMM, 3-buffer B / 1 barrier per tile ----------
// R7-verified (90.2 us, 0 conflicts, MfmaUtil 38%). Untouched.
__global__ __launch_bounds__(512, 2) void gemm256(const u16* __restrict__ A,
                                                  const u16* __restrict__ Bt,
                                                  u16* __restrict__ C,
                                                  int M, int N, int K) {
  __shared__ u16 As[2][256 * 64];  // 64 KiB
  __shared__ u16 Bs[3][256 * 64];  // 96 KiB
  const int tid = threadIdx.x;
  const int w = tid >> 6, l = tid & 63, la = l & 15, qd = l >> 4;
  const int wr = w >> 2, wc = w & 3;

  const int nbx = gridDim.x;
  const int nwg = nbx * gridDim.y;
  int lin = blockIdx.y * nbx + blockIdx.x;
  if ((nwg & 7) == 0) lin = (lin & 7) * (nwg >> 3) + (lin >> 3);
  const int m0 = (lin / nbx) * 256, n0 = (lin % nbx) * 256;
  const int NT = K >> 6;

  const int sx0 = (qd ^ (la & 7)) * 8;
  const int sx1 = ((4 + qd) ^ (la & 7)) * 8;
  const int gsw = ((tid & 7) ^ ((tid >> 3) & 7)) * 8;

  f32x4 acc[8][4] = {};

  auto issue = [&](int s) {
    if (s >= NT * 4) return;
    const int kt = s >> 2, part = s & 3;
    const int h = part & 1;
    const u16* G = (part >= 2) ? A : Bt;
    const int b0 = (part >= 2) ? m0 : n0;
    u16* L = ((part >= 2) ? &As[kt & 1][0] : &Bs[kt % 3][0]) + h * 8192;
    const int k0 = kt << 6;
#pragma unroll
    for (int q = 0; q < 2; ++q) {
      const int row = h * 128 + q * 64 + (tid >> 3);
      const u16* g = G + (size_t)(b0 + row) * K + k0 + gsw;
      stage16(g, L + (q * 512 + w * 64) * 8, l);
    }
  };

  auto readA = [&](int buf, int mh, short8(&af)[4][2]) {
    const u16* base = &As[buf][0];
#pragma unroll
    for (int i = 0; i < 4; ++i) {
      const int ro = (wr * 128 + mh * 64 + i * 16 + la) * 64;
      af[i][0] = *(const short8*)(base + ro + sx0);
      af[i][1] = *(const short8*)(base + ro + sx1);
    }
  };
  auto readB = [&](int buf, int nh, short8(&bf)[2][2]) {
    const u16* base = &Bs[buf][0];
#pragma unroll
    for (int j = 0; j < 2; ++j) {
      const int ro = (wc * 64 + nh * 32 + j * 16 + la) * 64;
      bf[j][0] = *(const short8*)(base + ro + sx0);
      bf[j][1] = *(const short8*)(base + ro + sx1);
    }
  };
  auto quad = [&](short8(&af)[4][2], short8(&bf)[2][2], int mh, int nh) {
#pragma unroll
    for (int kk = 0; kk < 2; ++kk)
#pragma unroll
      for (int i = 0; i < 4; ++i)
#pragma unroll
        for (int jj = 0; jj < 2; ++jj)
          acc[mh * 4 + i][nh * 2 + jj] =
              MFMA(af[i][kk], bf[jj][kk], acc[mh * 4 + i][nh * 2 + jj]);
  };

#pragma unroll
  for (int s = 0; s < 6; ++s) issue(s);
  asm volatile("s_waitcnt vmcnt(4)" ::: "memory");
  __builtin_amdgcn_s_barrier();

  for (int t = 0; t < NT; ++t) {
    const int ab = t & 1, bb = t % 3;
    short8 af[4][2], af2[4][2], bf0[2][2], bf1[2][2];
    readA(ab, 0, af);
    sched_barrier0();
    readB(bb, 0, bf0);
    sched_barrier0();
    readB(bb, 1, bf1);
    sched_barrier0();
    issue(4 * t + 6);
    issue(4 * t + 7);
    issue(4 * t + 8);
    issue(4 * t + 9);
    asm volatile("s_waitcnt lgkmcnt(4)" ::: "memory");
    sched_barrier0();
    readA(ab, 1, af2);
    sched_barrier0();
    __builtin_amdgcn_s_setprio(1);
    quad(af, bf0, 0, 0);
    __builtin_amdgcn_s_setprio(0);
    asm volatile("s_waitcnt lgkmcnt(8)" ::: "memory");
    sched_barrier0();
    __builtin_amdgcn_s_setprio(1);
    quad(af, bf1, 0, 1);
    __builtin_amdgcn_s_setprio(0);
    asm volatile("s_waitcnt lgkmcnt(0)" ::: "memory");
    sched_barrier0();
    __builtin_amdgcn_s_setprio(1);
    quad(af2, bf0, 1, 0);
    quad(af2, bf1, 1, 1);
    __builtin_amdgcn_s_setprio(0);
    asm volatile("s_waitcnt vmcnt(4)" ::: "memory");
    __builtin_amdgcn_s_barrier();
  }

#pragma unroll
  for (int i = 0; i < 8; ++i)
#pragma unroll
    for (int j = 0; j < 4; ++j) {
      const int r0 = m0 + wr * 128 + i * 16 + qd * 4;
      const int c0 = n0 + wc * 64 + j * 16 + la;
#pragma unroll
      for (int r = 0; r < 4; ++r)
        C[(size_t)(r0 + r) * N + c0] = f2bf(acc[i][j][r]);
    }
}

// ---------- RoPE prep ----------
__global__ __launch_bounds__(256) void rope_prep(const u16* __restrict__ qkv,
                                                 const int* __restrict__ pos,
                                                 u16* __restrict__ Qh,
                                                 u16* __restrict__ Kt) {
  const int s = blockIdx.x;
  const int h = blockIdx.y * 4 + (threadIdx.x >> 6);
  const int t = threadIdx.x & 63;
  const size_t qin = (size_t)s * N3 + h * HD;
  const size_t kin = qin + HID;
  const size_t ob = ((size_t)h * S_LEN + s) * HDP;
  const size_t kb = ((size_t)(h * 32) + (s >> 6)) * 6144 + (size_t)(s & 63) * 8;
  if (t < 32) {
    const float p = (float)pos[s];
    const float inv = exp2f(-(float)t * (13.287712379549449f / 32.0f));
    const float ang = p * inv;
    const float cs = cosf(ang), sn = sinf(ang);
    float x1 = bf2f(qkv[qin + t]), x2 = bf2f(qkv[qin + t + 32]);
    Qh[ob + t] = f2bf(x1 * cs - x2 * sn);
    Qh[ob + t + 32] = f2bf(x2 * cs + x1 * sn);
    x1 = bf2f(qkv[kin + t]);
    x2 = bf2f(qkv[kin + t + 32]);
    Kt[kb + (size_t)(t >> 3) * 512 + (t & 7)] = f2bf(x1 * cs - x2 * sn);
    const int d2 = t + 32;
    Kt[kb + (size_t)(d2 >> 3) * 512 + (d2 & 7)] = f2bf(x2 * cs + x1 * sn);
  } else if (t < 48) {
    const int d = t + 32;  // 64..79 pass-through
    Qh[ob + d] = qkv[qin + d];
    Kt[kb + (size_t)(d >> 3) * 512 + (d & 7)] = qkv[kin + d];
  } else {
    const int d = t + 32;  // 80..95 zero pad
    Qh[ob + d] = 0;
    Kt[kb + (size_t)(d >> 3) * 512 + (d & 7)] = 0;
  }
}

// ---------- Fused causal+ALiBi flash attention, VALU-trimmed softmax ----------
// Structure as R8 (uniform sub-block pairs, 256 thr, 2 blocks/CU). Softmax
// rewritten for VALU (was 49.5% VALUBusy vs 17% MfmaUtil):
//  * s2K[j] = slope2*K_j precomputed per block; per-iter scalar
//    sb = slope2*base - m_i folds bias AND running max into ONE fma per elem.
//  * m_i starts at 0 (not -1e30): defer-max keeps v<=8 (p<=256) as before;
//    far-past tiles underflow exp2 to exactly 0 (their true weights are
//    ~e^-1000, negligible); row max >= diagonal score so l_i never underflows.
//  * bf16 pack via (__bf16) casts -> compiler emits v_cvt_pk_bf16_f32 (RNE),
//    ~8 ops/iter instead of ~96 for the manual f2bf bit-twiddle.
__global__ __launch_bounds__(256) void attn_fused(const u16* __restrict__ Qh,
                                                  const u16* __restrict__ Kt,
                                                  const u16* __restrict__ Vt,
                                                  u16* __restrict__ AO) {
  __shared__ u16 Ks[2][768 * 8];  // 2 x 12288 B (12 slots x 64 rows x 16 B)
  __shared__ u16 Vs[2][640 * 8];  // 2 x 10240 B (swizzled columns)
  const int tid = threadIdx.x, w = tid >> 6, l = tid & 63;
  const int la = l & 15, qd = l >> 4;
  const int h = blockIdx.y;
  const int x = blockIdx.x;  // 0..15
  const int pair = x >> 1;
  const int half = (x & 1) ^ (h >> 4);
  const int q0A = (15 - pair) * 128 + half * 64;  // long segment first
  const int q0B = pair * 128 + half * 64;
  const int nItA = (q0A >> 6) + 1;
  const int nItB = (q0B >> 6) + 1;
  const size_t hS = (size_t)h * S_LEN;

  short8 qfA[3], qfB[3];
#pragma unroll
  for (int c = 0; c < 3; ++c) {
    qfA[c] = *(const short8*)&Qh[(hS + q0A + w * 16 + la) * HDP + c * 32 + qd * 8];
    qfB[c] = *(const short8*)&Qh[(hS + q0B + w * 16 + la) * HDP + c * 32 + qd * 8];
  }

  const float slope2 = exp2f(-0.25f * (float)(h + 1)) * LOG2E;
  const float scl2 = QK_SCALE * LOG2E;
  float s2K[16];
#pragma unroll
  for (int kt = 0; kt < 4; ++kt)
#pragma unroll
    for (int r = 0; r < 4; ++r) s2K[kt * 4 + r] = slope2 * (float)(kt * 16 + r);

  float m_i = 0.f, l_i = 0.f;
  f32x4 acc[5] = {};

  const u16* gK = Kt + (size_t)h * 32 * 6144;
  const u16* gV = Vt + (size_t)h * HD * S_LEN;

  auto stage = [&](int kt_g, int buf) {
    const u16* gkt = gK + (size_t)kt_g * 6144;
#pragma unroll
    for (int j = 0; j < 3; ++j)
      stage16(gkt + (size_t)(j * 256 + tid) * 8, &Ks[buf][(j * 256 + w * 64) * 8], l);
    const u16* gv = gV + (kt_g << 6);
#pragma unroll
    for (int j = 0; j < 3; ++j) {
      const int c0 = j * 256 + w * 64;
      if (c0 < 640) {  // wave-uniform guard
        const int c = c0 + l;
        const int row = c >> 3, seg = c & 7;
        const int gcol = ((seg - (row & 7)) & 7) * 8;
        stage16(gv + (size_t)row * S_LEN + gcol, &Vs[buf][c0 * 8], l);
      }
    }
  };

  int g = 0;  // global iteration counter (buffer parity across segments)
  stage(0, 0);

  auto run_seg = [&](const short8(&qf)[3], int q0, int nIt, bool more) {
    const int qb = q0 + w * 16;
    const int q = qb + la;
    for (int it = 0; it < nIt; ++it, ++g) {
      const int buf = g & 1;
      __syncthreads();  // stage(g) complete; all waves done with buf^1
      if (it + 1 < nIt) stage(it + 1, buf ^ 1);
      else if (more) stage(0, buf ^ 1);  // restart key stream for next segment
      const int k0 = it << 6;
      if (k0 >= qb + 16) continue;  // wave-uniform skip of fully-masked tiles

      // --- S^T tiles from LDS (lane-contiguous reads of the tiled K) ---
      f32x4 st[4];
#pragma unroll
      for (int kt = 0; kt < 4; ++kt) {
        short8 kf[3];
#pragma unroll
        for (int c = 0; c < 3; ++c)
          kf[c] = *(const short8*)&Ks[buf][((c * 4 + qd) * 64 + kt * 16 + la) * 8];
        f32x4 z = {};
#pragma unroll
        for (int c = 0; c < 3; ++c) z = MFMA(kf[c], qf[c], z);
        st[kt] = z;
      }

      // --- mask + scale, log2 domain, m_i folded: v = score*log2e - m_i ---
      const float base = (float)(k0 + qd * 4 - q);  // rel = base + K_j
      const float sb = fmaf(slope2, base, -m_i);
      float v[4][4];
      float mloc = -1e30f;
      if (k0 + 64 <= qb + 1) {  // tile fully unmasked for every lane of wave
#pragma unroll
        for (int kt = 0; kt < 4; ++kt)
#pragma unroll
          for (int r = 0; r < 4; ++r) {
            const float t = fmaf(st[kt][r], scl2, sb + s2K[kt * 4 + r]);
            v[kt][r] = t;
            mloc = fmaxf(mloc, t);
          }
      } else {
#pragma unroll
        for (int kt = 0; kt < 4; ++kt)
#pragma unroll
          for (int r = 0; r < 4; ++r) {
            const float t = fmaf(st[kt][r], scl2, sb + s2K[kt * 4 + r]);
            const float tv = (base <= -(float)(kt * 16 + r)) ? t : -1e30f;
            v[kt][r] = tv;
            mloc = fmaxf(mloc, tv);
          }
      }
      mloc = fmaxf(mloc, __shfl_xor(mloc, 16));
      mloc = fmaxf(mloc, __shfl_xor(mloc, 32));

      // --- defer-max (T13): mloc is already relative to m_i ---
      if (!__all(mloc <= 8.0f)) {
        const float d = fmaxf(mloc, 0.f);
        const float al = exp2f(-d);
        m_i += d;
        l_i *= al;
#pragma unroll
        for (int dt = 0; dt < 5; ++dt) acc[dt] *= al;
#pragma unroll
        for (int kt = 0; kt < 4; ++kt)
#pragma unroll
          for (int r = 0; r < 4; ++r) v[kt][r] -= d;
      }

      float ps = 0.f;
      short4v pf[4];
#pragma unroll
      for (int kt = 0; kt < 4; ++kt) {
        bhalf4 pb;
#pragma unroll
        for (int r = 0; r < 4; ++r) {
          const float pv = exp2f(v[kt][r]);
          ps += pv;
          pb[r] = (__bf16)pv;  // -> v_cvt_pk_bf16_f32 (RNE)
        }
        pf[kt] = __builtin_bit_cast(short4v, pb);
      }
      ps += __shfl_xor(ps, 16);
      ps += __shfl_xor(ps, 32);
      l_i += ps;

      // --- PV from LDS (swizzled, conflict-free b64): O^T += V^T * P^T ---
      const int cb = qd * 4 + ((la & 7) << 3);
#pragma unroll
      for (int dt = 0; dt < 5; ++dt) {
        const int vrow = (dt * 16 + la) * 64;
#pragma unroll
        for (int kt = 0; kt < 4; ++kt) {
          const short4v vf = *(const short4v*)&Vs[buf][vrow + ((kt * 16 + cb) & 63)];
          acc[dt] = MFMA16(vf, pf[kt], acc[dt]);
        }
      }
    }
    // --- epilogue for this segment: lane holds O^T[d=dt*16+qd*4+r][q] ---
    const float inv = 1.0f / l_i;
    const size_t row = (size_t)q;
#pragma unroll
    for (int dt = 0; dt < 5; ++dt) {
      us4 o;
#pragma unroll
      for (int r = 0; r < 4; ++r) o[r] = f2bf(acc[dt][r] * inv);
      *(us4*)&AO[row * HID + h * HD + dt * 16 + qd * 4] = o;
    }
    m_i = 0.f;
    l_i = 0.f;
#pragma unroll
    for (int dt = 0; dt < 5; ++dt) acc[dt] = f32x4{};
  };

  run_seg(qfA, q0A, nItA, true);
  run_seg(qfB, q0B, nItB, false);
}

extern "C" void kernel_launch(void* const* d_in, const int* in_sizes, int n_in,
                              void* d_out, int out_size, void* d_ws, size_t ws_size,
                              hipStream_t stream) {
  const int* pos = (const int*)d_in[0];
  const void* hidden = d_in[1];
  const void* w_qkv = d_in[2];
  const void* w_out = d_in[3];
  u16* ws = (u16*)d_ws;

  // ws layout (u16 elements). Hb dead after GEMM1 -> Vt aliases it (same size).
  // WtQ dead after GEMM1 -> Qh/Kh/AO alias into it (17.8M <= 19.66M).
  u16* Hb = ws;                                  //  5,242,880
  u16* WtQ = Hb + (size_t)S_LEN * HID;           // 19,660,800
  u16* WtO = WtQ + (size_t)N3 * HID;             //  6,553,600
  u16* qkv = WtO + (size_t)HID * HID;            // 15,728,640
  int* flag = (int*)(qkv + (size_t)S_LEN * N3);  // 1 int
  u16* Vt = Hb;                                  //  5,242,880 (alias)
  u16* Qh = WtQ;                                 //  6,291,456 (alias)
  u16* Kh = Qh + (size_t)NHEAD * S_LEN * HDP;    //  6,291,456 (alias, tiled layout)
  u16* AO = Kh + (size_t)NHEAD * S_LEN * HDP;    //  5,242,880 (alias)

  detect_dtype<<<1, 256, 0, stream>>>((const u32*)hidden, flag);
  convert_hidden<<<(S_LEN * HID / 4 + 255) / 256, 256, 0, stream>>>(hidden, Hb,
                                                                    S_LEN * HID / 4, flag);
  // fused: w_qkv [HID][N3] -> WtQ and w_out [HID][HID] -> WtO
  transpose_w2<<<dim3(N3 / 64 + HID / 64, HID / 64), 256, 0, stream>>>(w_qkv, WtQ, w_out,
                                                                       WtO, flag);
  gemm256<<<dim3(N3 / 256, S_LEN / 256), 512, 0, stream>>>(Hb, WtQ, qkv, S_LEN, N3, HID);
  // qkv[s][2*HID + c] -> Vt[c][s]
  transpose64<<<dim3(HID / 64, S_LEN / 64), 256, 0, stream>>>(qkv, Vt, N3, 2 * HID, S_LEN,
                                                              nullptr);
  rope_prep<<<dim3(S_LEN, NHEAD / 4), 256, 0, stream>>>(qkv, pos, Qh, Kh);
  attn_fused<<<dim3(16, NHEAD), 256, 0, stream>>>(Qh, Kh, Vt, AO);
  gemm128c<<<dim3(HID / 128, S_LEN / 128), 256, 0, stream>>>(AO, WtO, d_out, S_LEN, HID,
                                                             HID, flag);
}